// Round 11
// baseline (1396.249 us; speedup 1.0000x reference)
//
#include <hip/hip_runtime.h>
#include <math.h>

#define CC 128
#define HH 4
#define LL 3
#define LNEPS 1e-5f

typedef unsigned int u32;
typedef unsigned short ushort;
typedef float f32x16 __attribute__((ext_vector_type(16)));
typedef __bf16 bf16x8 __attribute__((ext_vector_type(8)));
union Frag { uint4 q; bf16x8 b; };

__device__ __forceinline__ ushort bf16rne(float x){ u32 u=__float_as_uint(x); return (ushort)((u + 0x7FFF + ((u>>16)&1))>>16); }
__device__ __forceinline__ float bf2f(ushort h){ return __uint_as_float(((u32)h)<<16); }

// ---------------- tiny precompute kernels ----------------

__global__ void k_att_collapse(const float* __restrict__ W, const float* __restrict__ att, float* __restrict__ out){
  int idx = blockIdx.x*blockDim.x + threadIdx.x;
  if(idx >= LL*CC*HH) return;
  int h = idx % HH; int k = (idx/HH)%CC; int l = idx/(HH*CC);
  const float* w = W + ((size_t)(l*CC+k))*(HH*CC) + h*CC;
  const float* a = att + (size_t)(l*HH+h)*CC;
  float s=0.f;
  for(int c=0;c<CC;c++) s += w[c]*a[c];
  out[idx] = s;
}

__global__ void k_We(const float* __restrict__ w_ee, const float* __restrict__ w_ep, float* __restrict__ We){
  int idx = blockIdx.x*blockDim.x + threadIdx.x;
  if(idx >= 4*CC) return;
  int c = idx & (CC-1); int k = idx >> 7;
  float s=0.f;
  for(int m=0;m<CC;m++) s += w_ee[k*CC+m]*w_ep[m*CC+c];
  We[idx]=s;
}

__global__ void k_be_vemb(const float* __restrict__ b_ee, const float* __restrict__ w_ep, const float* __restrict__ b_ep,
                          const float* __restrict__ vnf, const float* __restrict__ w_vnf, const float* __restrict__ b_vnf,
                          float* __restrict__ be, float* __restrict__ vemb){
  int t = threadIdx.x;
  if(t<CC){
    float s=b_ep[t];
    for(int m=0;m<CC;m++) s += b_ee[m]*w_ep[m*CC+t];
    be[t]=s;
  } else if(t<2*CC){
    int c=t-CC;
    float s=b_vnf[c];
    for(int j=0;j<6;j++) s += vnf[j]*w_vnf[j*CC+c];
    vemb[c]=s;
  }
}

__global__ void k_h1eff(const float* __restrict__ We, const float* __restrict__ be, const float* __restrict__ vemb,
                        const float* __restrict__ w1, const float* __restrict__ b1,
                        float* __restrict__ Wh1, float* __restrict__ bh1){
  int idx = blockIdx.x*blockDim.x + threadIdx.x;
  if(idx < 4*CC){
    int c = idx & (CC-1); int k = idx>>7;
    float s=0.f;
    for(int m=0;m<CC;m++) s += We[k*CC+m]*w1[m*CC+c];
    Wh1[idx]=s;
  } else if(idx < 5*CC){
    int c = idx - 4*CC;
    float s=b1[c];
    for(int m=0;m<CC;m++) s += be[m]*w1[m*CC+c];
    for(int j=0;j<CC;j++) s += vemb[j]*w1[(CC+j)*CC+c];
    bh1[c]=s;
  }
}

__global__ void k_aelin(const float* __restrict__ We, const float* __restrict__ be, const float* __restrict__ wattE,
                        float* __restrict__ aelin, float* __restrict__ aebias){
  int t = threadIdx.x;
  if(t<48){
    int l=t>>4, k=(t>>2)&3, h=t&3;
    float s=0.f;
    for(int m=0;m<CC;m++) s += We[k*CC+m]*wattE[(size_t)(l*CC+m)*HH+h];
    aelin[t]=s;
  } else if(t<60){
    int i=t-48; int l=i>>2, h=i&3;
    float s=0.f;
    for(int m=0;m<CC;m++) s += be[m]*wattE[(size_t)(l*CC+m)*HH+h];
    aebias[i]=s;
  }
}

// split + transpose + MFMA-tile W, hi/lo interleaved: [subtile(c/32*64+hk/8)][c%32][8 hi | 8 lo]
__global__ void k_wsplit(const float* __restrict__ gat_w, ushort* __restrict__ BT){
  int idx = blockIdx.x*blockDim.x + threadIdx.x;
  if(idx >= LL*512*CC) return;
  int l = idx >> 16;
  int r = idx & 65535;
  int hk = r >> 7;
  int c  = r & 127;
  int k = hk & 127, h = hk >> 7;
  float v = gat_w[((size_t)(l*CC + k))*(HH*CC) + h*CC + c] * 0.25f;
  ushort hi = bf16rne(v);
  ushort lo = bf16rne(v - bf2f(hi));
  size_t pos = (size_t)l*131072 + ((size_t)(c>>5)*64 + (hk>>3))*512 + (size_t)((c&31)*16 + (hk&7));
  BT[pos]=hi; BT[pos+8]=lo;
}

// w2 [128 k][64 o] -> B-fragment tiles: [(o/32)*16 + k/8][o%32][8 hi | 8 lo]
__global__ void k_w2split(const float* __restrict__ w2, ushort* __restrict__ W2T){
  int idx = blockIdx.x*blockDim.x + threadIdx.x;
  if(idx >= 128*64) return;
  int k = idx>>6, o = idx&63;
  float v = w2[idx];
  ushort hi = bf16rne(v);
  ushort lo = bf16rne(v - bf2f(hi));
  size_t pos = ((size_t)(o>>5)*16 + (k>>3))*512 + (size_t)((o&31)*16 + (k&7));
  W2T[pos]=hi; W2T[pos+8]=lo;
}

__global__ void k_vvec(const float* __restrict__ vnf, const float* __restrict__ w1, const float* __restrict__ b1,
                       const float* __restrict__ w2, const float* __restrict__ b2, float* __restrict__ v){
  __shared__ float hv[CC];
  int t=threadIdx.x;
  float s=b1[t];
  for(int j=0;j<6;j++) s += vnf[j]*w1[j*CC+t];
  hv[t]=fmaxf(s,0.f);
  __syncthreads();
  float o=b2[t];
  for(int j=0;j<CC;j++) o += hv[j]*w2[j*CC+t];
  v[t]=o;
}

// ---------------- node embedding ----------------
__global__ void k_node_embed(const float* __restrict__ x, const float* __restrict__ w, const float* __restrict__ b,
                             float* __restrict__ xh, int N){
  int idx=blockIdx.x*blockDim.x+threadIdx.x;
  if(idx>=N*CC) return;
  int c=idx&(CC-1); int n=idx>>7;
  const float* xr = x+(size_t)n*8;
  float s=b[c];
  #pragma unroll
  for(int k=0;k<8;k++) s += xr[k]*w[k*CC+c];
  xh[idx]=s;
}

// ---------------- CSR by dst (hierarchical scan) ----------------
__global__ void k_count(const int* __restrict__ dst, int* __restrict__ counts, int E){
  int e=blockIdx.x*blockDim.x+threadIdx.x;
  if(e<E) atomicAdd(&counts[dst[e]],1);
}

__global__ __launch_bounds__(256) void k_scan_blk(const int* __restrict__ counts, int* __restrict__ offsets,
                                                  int* __restrict__ bsum, int N){
  __shared__ int sv[256];
  int t=threadIdx.x; int i=blockIdx.x*256+t;
  int v = (i<N)? counts[i] : 0;
  sv[t]=v;
  __syncthreads();
  for(int off=1;off<256;off<<=1){
    int add = (t>=off)? sv[t-off]:0;
    __syncthreads();
    sv[t]+=add;
    __syncthreads();
  }
  if(i<N) offsets[i]=sv[t]-v;
  if(t==255) bsum[blockIdx.x]=sv[255];
}

__global__ __launch_bounds__(1024) void k_scan_top(int* __restrict__ bsum, int nb){
  __shared__ int sv[1024];
  int t=threadIdx.x;
  int v = (t<nb)? bsum[t] : 0;
  sv[t]=v;
  __syncthreads();
  for(int off=1;off<1024;off<<=1){
    int add = (t>=off)? sv[t-off]:0;
    __syncthreads();
    sv[t]+=add;
    __syncthreads();
  }
  if(t<nb) bsum[t]=sv[t]-v;
}

__global__ void k_scan_add(int* __restrict__ offsets, const int* __restrict__ bsum, int N, int E){
  int i=blockIdx.x*blockDim.x+threadIdx.x;
  if(i<N) offsets[i]+=bsum[i>>8];
  if(i==0) offsets[N]=E;
}

__global__ void k_fill(const int* __restrict__ dst, const int* __restrict__ offsets, int* __restrict__ cursor,
                       int* __restrict__ elist, int E){
  int e=blockIdx.x*blockDim.x+threadIdx.x;
  if(e<E){ int d=dst[e]; int pos=atomicAdd(&cursor[d],1); elist[offsets[d]+pos]=e; }
}

// ---------------- MFMA edge-attention MLP -> a_e[l][e][h] ----------------
__global__ __launch_bounds__(128) void k_edge_attn(
    const float* __restrict__ edge_attr,
    const float* __restrict__ Wh1, const float* __restrict__ bh1,
    const ushort* __restrict__ W2T, const float* __restrict__ attn_b2,
    const float* __restrict__ attn_w3, const float* __restrict__ attn_b3,
    const float* __restrict__ aelin, const float* __restrict__ aebias,
    float* __restrict__ a_e, int E)
{
  __shared__ __align__(16) ushort h1f[2][16][32][16];
  __shared__ float s_wh1[640];
  __shared__ float s_ea[64][4];
  __shared__ float s_att[64];
  int t = threadIdx.x;
  int e0 = blockIdx.x*64;
  for(int i=t;i<640;i+=128) s_wh1[i] = (i<512)? Wh1[i] : bh1[i-512];
  if(t<64){
    int e=e0+t;
    float4 v = (e<E)? *(const float4*)&edge_attr[(size_t)e*4] : make_float4(0.f,0.f,0.f,0.f);
    s_ea[t][0]=v.x; s_ea[t][1]=v.y; s_ea[t][2]=v.z; s_ea[t][3]=v.w;
  }
  __syncthreads();
  for(int c=t; c<1024; c+=128){
    int e = c&63, kc = c>>6;
    int et = e>>5, row = e&31;
    float ea0=s_ea[e][0], ea1=s_ea[e][1], ea2=s_ea[e][2], ea3=s_ea[e][3];
    ushort hibuf[8], lobuf[8];
    #pragma unroll
    for(int j=0;j<8;j++){
      int k = kc*8+j;
      float v = s_wh1[512+k] + ea0*s_wh1[k] + ea1*s_wh1[128+k] + ea2*s_wh1[256+k] + ea3*s_wh1[384+k];
      v = fmaxf(v, 0.f);
      ushort hi = bf16rne(v);
      hibuf[j]=hi; lobuf[j]=bf16rne(v - bf2f(hi));
    }
    *(uint4*)&h1f[et][kc][row][0] = *(const uint4*)hibuf;
    *(uint4*)&h1f[et][kc][row][8] = *(const uint4*)lobuf;
  }
  __syncthreads();
  int wave=t>>6, lane=t&63;
  int rlane = lane&31, khalf = lane>>5;
  int et = wave;
  f32x16 acc[2];
  #pragma unroll
  for(int o=0;o<2;o++)
    #pragma unroll
    for(int j=0;j<16;j++) acc[o][j]=0.f;
  for(int ks=0; ks<8; ++ks){
    int kq = ks*2 + khalf;
    Frag ah, al;
    ah.q = *(const uint4*)&h1f[et][kq][rlane][0];
    al.q = *(const uint4*)&h1f[et][kq][rlane][8];
    #pragma unroll
    for(int o=0;o<2;o++){
      size_t bb = ((size_t)(o*16 + kq))*512 + (size_t)(rlane*16);
      Frag bh, bl;
      bh.q = *(const uint4*)(W2T + bb);
      bl.q = *(const uint4*)(W2T + bb + 8);
      acc[o] = __builtin_amdgcn_mfma_f32_32x32x16_bf16(ah.b, bh.b, acc[o], 0,0,0);
      acc[o] = __builtin_amdgcn_mfma_f32_32x32x16_bf16(ah.b, bl.b, acc[o], 0,0,0);
      acc[o] = __builtin_amdgcn_mfma_f32_32x32x16_bf16(al.b, bh.b, acc[o], 0,0,0);
    }
  }
  float b2c0 = attn_b2[rlane], b2c1 = attn_b2[rlane+32];
  float w3c0 = attn_w3[rlane], w3c1 = attn_w3[rlane+32];
  float b3v = attn_b3[0];
  #pragma unroll
  for(int reg=0; reg<16; ++reg){
    float val = fmaxf(acc[0][reg]+b2c0,0.f)*w3c0 + fmaxf(acc[1][reg]+b2c1,0.f)*w3c1;
    #pragma unroll
    for(int off=1; off<32; off<<=1) val += __shfl_xor(val, off);
    int rloc = (reg&3) + 8*(reg>>2) + 4*khalf;
    if(rlane==0) s_att[et*32 + rloc] = 1.f/(1.f+expf(-(val + b3v)));
  }
  __syncthreads();
  if(t<64){
    int e = e0+t;
    if(e<E){
      float att = s_att[t];
      float ea0=s_ea[t][0], ea1=s_ea[t][1], ea2=s_ea[t][2], ea3=s_ea[t][3];
      #pragma unroll
      for(int l=0;l<LL;l++){
        float4 v;
        float* out=(float*)&v;
        #pragma unroll
        for(int h=0;h<4;h++){
          out[h] = att*(ea0*aelin[(l*4+0)*4+h] + ea1*aelin[(l*4+1)*4+h]
                      + ea2*aelin[(l*4+2)*4+h] + ea3*aelin[(l*4+3)*4+h] + aebias[l*4+h]);
        }
        *(float4*)&a_e[((size_t)l*E+e)*4] = v;
      }
    }
  }
}

// ---------------- per-node attention logits (LDS-staged) ----------------
__global__ __launch_bounds__(256) void k_node_ad(const float* __restrict__ xh, const float* __restrict__ wS, const float* __restrict__ wD,
                          float* __restrict__ asrc, float* __restrict__ adst, int N){
  __shared__ float sx[32*129];
  __shared__ float sw[CC*8];
  int t = threadIdx.x;
  int n0 = blockIdx.x*32;
  for(int i=t;i<512;i+=256){ int k=i>>2, h=i&3; sw[k*8+h]=wS[i]; sw[k*8+4+h]=wD[i]; }
  int lim = (N-n0 < 32 ? N-n0 : 32)*128;
  for(int i=t;i<lim;i+=256){ int nl=i>>7, k=i&127; sx[nl*129+k] = xh[(size_t)n0*128 + i]; }
  __syncthreads();
  int node = t>>3, o = t&7;
  if(n0+node < N){
    const float* xr = sx + node*129;
    float s=0.f;
    #pragma unroll 8
    for(int k=0;k<CC;k++) s += xr[k]*sw[k*8+o];
    ((o<4)? asrc : adst)[(n0+node)*4 + (o&3)] = s;
  }
}

// ---------------- per-(node,head) softmax normalize of a_e (in place) ----------------
__global__ void k_alpha(const float* __restrict__ asrc, const float* __restrict__ adst,
                        const int* __restrict__ offsets, const int* __restrict__ elist,
                        const int* __restrict__ srcArr, float* __restrict__ ael, int N){
  int idx = blockIdx.x*blockDim.x + threadIdx.x;
  if(idx >= N*4) return;
  int n = idx>>2, h = idx&3;
  int beg = offsets[n], end = offsets[n+1];
  if(beg==end) return;
  float ad = adst[n*4+h];
  float m = -1e30f;
  for(int i=beg;i<end;i++){
    int e = elist[i];
    float a = asrc[srcArr[e]*4+h] + ad + ael[e*4+h];
    a = (a>0.f)? a : 0.2f*a;
    m = fmaxf(m,a);
  }
  float s=0.f;
  for(int i=beg;i<end;i++){
    int e = elist[i];
    float a = asrc[srcArr[e]*4+h] + ad + ael[e*4+h];
    a = (a>0.f)? a : 0.2f*a;
    float ex = expf(a-m);
    s += ex;
    ael[e*4+h] = ex;
  }
  float inv = 1.f/(s+1e-16f);
  for(int i=beg;i<end;i++){
    int e = elist[i];
    ael[e*4+h] *= inv;
  }
}

// ---------------- FUSED: gather-aggregate -> LDS A-tile -> MFMA GEMM -> LN -> residual ----------------
// block = 256 thr / 4 waves, 32 nodes; sA[kq][row][8hi|8lo] = 64 KB
__global__ __launch_bounds__(256) void k_agg_gemm(
    const float* __restrict__ xin, const int* __restrict__ srcArr,
    const float* __restrict__ alpha, const int* __restrict__ offsets, const int* __restrict__ elist,
    const ushort* __restrict__ BT,
    const float* __restrict__ bias, const float* __restrict__ lng, const float* __restrict__ lnb,
    float* __restrict__ xout, int N)
{
  __shared__ __align__(16) ushort sA[64][32][16];
  int t = threadIdx.x;
  int wave = t>>6, lane = t&63;
  int n0 = blockIdx.x*32;
  const float4* al4 = (const float4*)alpha;
  // phase 1: gather 8 nodes per wave
  for(int j=0;j<8;j++){
    int r = wave*8+j;
    int n = n0 + r;
    float2 ac[4];
    #pragma unroll
    for(int h=0;h<4;h++){ ac[h].x=0.f; ac[h].y=0.f; }
    if(n<N){
      int beg = offsets[n], end = offsets[n+1];
      for(int i=beg;i<end;i++){
        int e = elist[i];
        int sr = srcArr[e];
        float4 a = al4[e];
        float2 x = *(const float2*)&xin[(size_t)sr*CC + lane*2];
        ac[0].x += a.x*x.x; ac[0].y += a.x*x.y;
        ac[1].x += a.y*x.x; ac[1].y += a.y*x.y;
        ac[2].x += a.z*x.x; ac[2].y += a.z*x.y;
        ac[3].x += a.w*x.x; ac[3].y += a.w*x.y;
      }
    }
    #pragma unroll
    for(int h=0;h<4;h++){
      ushort h0 = bf16rne(ac[h].x), h1 = bf16rne(ac[h].y);
      u32 hi = (u32)h0 | ((u32)h1<<16);
      u32 lo = (u32)bf16rne(ac[h].x - bf2f(h0)) | ((u32)bf16rne(ac[h].y - bf2f(h1))<<16);
      int hk = h*CC + lane*2;
      int kq = hk>>3, off = hk&7;
      *(u32*)&sA[kq][r][off]   = hi;
      *(u32*)&sA[kq][r][off+8] = lo;
    }
  }
  __syncthreads();
  // phase 2: K-split GEMM, wave w covers kq in [16w, 16w+16)
  int rlane = lane&31, khalf = lane>>5;
  f32x16 acc[4];
  #pragma unroll
  for(int t4=0;t4<4;t4++)
    #pragma unroll
    for(int j=0;j<16;j++) acc[t4][j]=0.f;
  for(int ks=0; ks<8; ++ks){
    int kq = wave*16 + ks*2 + khalf;
    Frag ah, al;
    ah.q = *(const uint4*)&sA[kq][rlane][0];
    al.q = *(const uint4*)&sA[kq][rlane][8];
    #pragma unroll
    for(int t4=0;t4<4;t4++){
      size_t bb = ((size_t)(t4*64 + kq))*512 + (size_t)(rlane*16);
      Frag bh, bl;
      bh.q = *(const uint4*)(BT + bb);
      bl.q = *(const uint4*)(BT + bb + 8);
      acc[t4] = __builtin_amdgcn_mfma_f32_32x32x16_bf16(ah.b, bh.b, acc[t4], 0,0,0);
      acc[t4] = __builtin_amdgcn_mfma_f32_32x32x16_bf16(ah.b, bl.b, acc[t4], 0,0,0);
      acc[t4] = __builtin_amdgcn_mfma_f32_32x32x16_bf16(al.b, bh.b, acc[t4], 0,0,0);
    }
  }
  __syncthreads();
  // phase 3: waves 1-3 dump partials; wave 0 reduces + LN + residual
  if(wave>0){
    float* so = ((float*)sA) + (size_t)(wave-1)*4096;
    #pragma unroll
    for(int t4=0;t4<4;t4++)
      #pragma unroll
      for(int reg=0;reg<16;reg++){
        int rloc = (reg&3) + 8*(reg>>2) + 4*khalf;
        so[rloc*128 + t4*32 + rlane] = acc[t4][reg];
      }
  }
  __syncthreads();
  if(wave==0){
    const float* s0 = (const float*)sA;
    #pragma unroll
    for(int t4=0;t4<4;t4++)
      #pragma unroll
      for(int reg=0;reg<16;reg++){
        int rloc = (reg&3) + 8*(reg>>2) + 4*khalf;
        int idx = rloc*128 + t4*32 + rlane;
        acc[t4][reg] += s0[idx] + s0[4096+idx] + s0[8192+idx];
      }
    float bias4[4], g4[4], eb4[4];
    #pragma unroll
    for(int t4=0;t4<4;t4++){ int c=t4*32+rlane; bias4[t4]=bias[c]; g4[t4]=lng[c]; eb4[t4]=lnb[c]; }
    #pragma unroll
    for(int reg=0; reg<16; ++reg){
      int rloc = (reg&3) + 8*(reg>>2) + 4*khalf;
      int grow = n0 + rloc;
      float x0=acc[0][reg]+bias4[0];
      float x1=acc[1][reg]+bias4[1];
      float x2=acc[2][reg]+bias4[2];
      float x3=acc[3][reg]+bias4[3];
      float s = x0+x1+x2+x3;
      #pragma unroll
      for(int off=1; off<32; off<<=1) s += __shfl_xor(s, off);
      float mu = s*(1.f/CC);
      x0-=mu; x1-=mu; x2-=mu; x3-=mu;
      float q = x0*x0+x1*x1+x2*x2+x3*x3;
      #pragma unroll
      for(int off=1; off<32; off<<=1) q += __shfl_xor(q, off);
      float inv = rsqrtf(q*(1.f/CC)+LNEPS);
      if(grow < N){
        size_t gi = (size_t)grow*CC + rlane;
        xout[gi+ 0]  = x0*inv*g4[0] + eb4[0] + xin[gi+ 0];
        xout[gi+32]  = x1*inv*g4[1] + eb4[1] + xin[gi+32];
        xout[gi+64]  = x2*inv*g4[2] + eb4[2] + xin[gi+64];
        xout[gi+96]  = x3*inv*g4[3] + eb4[3] + xin[gi+96];
      }
    }
  }
}

// ---------------- Set2Set ----------------
__global__ __launch_bounds__(512) void k_lstm(const float* __restrict__ wih, const float* __restrict__ whh,
                    const float* __restrict__ bih, const float* __restrict__ bhh,
                    const float* __restrict__ qstar, float* __restrict__ hS, float* __restrict__ cS){
  __shared__ float sq[2*CC];
  __shared__ float sh[CC];
  __shared__ float sg[4*CC];
  int t=threadIdx.x;
  if(t<2*CC) sq[t]=qstar[t];
  else if(t<3*CC) sh[t-2*CC]=hS[t-2*CC];
  __syncthreads();
  float a=bih[t]+bhh[t];
  const float* wr = wih + (size_t)t*2*CC;
  for(int j=0;j<2*CC;j++) a += wr[j]*sq[j];
  const float* hr = whh + (size_t)t*CC;
  for(int j=0;j<CC;j++) a += hr[j]*sh[j];
  sg[t]=a;
  __syncthreads();
  if(t<CC){
    float gi=sg[t], gf=sg[CC+t], gg=sg[2*CC+t], go=sg[3*CC+t];
    float c = 1.f/(1.f+expf(-gf))*cS[t] + 1.f/(1.f+expf(-gi))*tanhf(gg);
    float h = 1.f/(1.f+expf(-go))*tanhf(c);
    cS[t]=c; hS[t]=h;
  }
}

__global__ __launch_bounds__(256) void k_s2s1(const float* __restrict__ xh, const float* __restrict__ q,
                                              float* __restrict__ pm, float* __restrict__ ps,
                                              float* __restrict__ pr, int N){
  int t=threadIdx.x, wave=t>>6, lane=t&63;
  float q0=q[lane], q1=q[lane+64];
  float m=-1e30f, s=0.f, r0=0.f, r1=0.f;
  for(int n=blockIdx.x*4+wave; n<N; n+=gridDim.x*4){
    const float* xr = xh+(size_t)n*CC;
    float x0 = xr[lane], x1 = xr[lane+64];
    float v = x0*q0 + x1*q1;
    #pragma unroll
    for(int o=32;o>=1;o>>=1) v += __shfl_xor(v,o);
    float nm = fmaxf(m,v);
    float f = expf(m-nm), g = expf(v-nm);
    s = s*f + g; r0 = r0*f + g*x0; r1 = r1*f + g*x1;
    m = nm;
  }
  __shared__ float sm[4], ss[4], sr[4][128];
  if(lane==0){ sm[wave]=m; ss[wave]=s; }
  sr[wave][lane]=r0; sr[wave][lane+64]=r1;
  __syncthreads();
  if(t<128){
    float M = fmaxf(fmaxf(sm[0],sm[1]),fmaxf(sm[2],sm[3]));
    float e0=expf(sm[0]-M), e1=expf(sm[1]-M), e2=expf(sm[2]-M), e3=expf(sm[3]-M);
    pr[(size_t)blockIdx.x*128+t] = sr[0][t]*e0 + sr[1][t]*e1 + sr[2][t]*e2 + sr[3][t]*e3;
    if(t==0){ pm[blockIdx.x]=M; ps[blockIdx.x]= ss[0]*e0+ss[1]*e1+ss[2]*e2+ss[3]*e3; }
  }
}

__global__ __launch_bounds__(1024) void k_s2s2(const float* __restrict__ pm, const float* __restrict__ ps,
                                               const float* __restrict__ pr, const float* __restrict__ hS,
                                               float* __restrict__ qstar, int NB){
  __shared__ float sM[256];
  __shared__ float sw[256];
  __shared__ float sS[256];
  __shared__ float srs[8][128];
  int t = threadIdx.x;
  if(t<256) sM[t] = (t<NB)? pm[t] : -1e30f;
  __syncthreads();
  for(int off=128; off>=1; off>>=1){
    if(t<off) sM[t] = fmaxf(sM[t], sM[t+off]);
    __syncthreads();
  }
  float M = sM[0];
  if(t<256){
    float w = (t<NB)? expf(pm[t]-M) : 0.f;
    sw[t] = w;
    sS[t] = (t<NB)? ps[t]*w : 0.f;
  }
  __syncthreads();
  for(int off=128; off>=1; off>>=1){
    if(t<off) sS[t] += sS[t+off];
    __syncthreads();
  }
  float ssum = sS[0];
  int g = t>>7, col = t&127;
  float rs = 0.f;
  for(int b=g; b<NB; b+=8) rs += pr[(size_t)b*128+col]*sw[b];
  srs[g][col] = rs;
  __syncthreads();
  if(t<128){
    float r = srs[0][t]+srs[1][t]+srs[2][t]+srs[3][t]+srs[4][t]+srs[5][t]+srs[6][t]+srs[7][t];
    qstar[t]    = hS[t];
    qstar[CC+t] = r/ssum;
  }
}

// ---------------- output MLP ----------------
__global__ __launch_bounds__(256) void k_out(
  const float* __restrict__ qstar, const float* __restrict__ vvec,
  const float* __restrict__ w1, const float* __restrict__ b1,
  const float* __restrict__ w2, const float* __restrict__ b2,
  const float* __restrict__ w3, const float* __restrict__ b3, float* __restrict__ out)
{
  __shared__ float comb[3*CC];
  __shared__ float o1[CC];
  __shared__ float o2[64];
  int t=threadIdx.x;
  if(t<2*CC) comb[t]=qstar[t];
  if(t<CC) comb[2*CC+t]=vvec[t];
  __syncthreads();
  if(t<CC){
    float a=b1[t];
    for(int j=0;j<3*CC;j++) a += comb[j]*w1[j*CC+t];
    o1[t]=fmaxf(a,0.f);
  }
  __syncthreads();
  if(t<64){
    float a=b2[t];
    for(int j=0;j<CC;j++) a += o1[j]*w2[j*64+t];
    o2[t]=fmaxf(a,0.f);
  }
  __syncthreads();
  {
    float a=b3[t];
    for(int j=0;j<64;j++) a += o2[j]*w3[j*256+t];
    out[t]=fmaxf(a,0.f);
  }
}

extern "C" void kernel_launch(void* const* d_in, const int* in_sizes, int n_in,
                              void* d_out, int out_size, void* d_ws, size_t ws_size,
                              hipStream_t stream){
  (void)n_in; (void)out_size; (void)ws_size;
  const float* x        = (const float*)d_in[0];
  const int*   eidx     = (const int*)  d_in[1];
  const float* edge_attr= (const float*)d_in[2];
  const float* vnf      = (const float*)d_in[3];
  const float* w_node   = (const float*)d_in[4];
  const float* b_node   = (const float*)d_in[5];
  const float* w_ee     = (const float*)d_in[6];
  const float* b_ee     = (const float*)d_in[7];
  const float* w_ep     = (const float*)d_in[8];
  const float* b_ep     = (const float*)d_in[9];
  const float* w_vnf    = (const float*)d_in[10];
  const float* b_vnf    = (const float*)d_in[11];
  const float* attn_w1  = (const float*)d_in[12];
  const float* attn_b1  = (const float*)d_in[13];
  const float* attn_w2  = (const float*)d_in[14];
  const float* attn_b2  = (const float*)d_in[15];
  const float* attn_w3  = (const float*)d_in[16];
  const float* attn_b3  = (const float*)d_in[17];
  const float* gat_w    = (const float*)d_in[18];
  const float* att_src  = (const float*)d_in[19];
  const float* att_dst  = (const float*)d_in[20];
  const float* gat_we   = (const float*)d_in[21];
  const float* att_e    = (const float*)d_in[22];
  const float* gat_b    = (const float*)d_in[23];
  const float* ln_g     = (const float*)d_in[24];
  const float* ln_b     = (const float*)d_in[25];
  const float* venc_w1  = (const float*)d_in[26];
  const float* venc_b1  = (const float*)d_in[27];
  const float* venc_w2  = (const float*)d_in[28];
  const float* venc_b2  = (const float*)d_in[29];
  const float* lstm_wih = (const float*)d_in[30];
  const float* lstm_whh = (const float*)d_in[31];
  const float* lstm_bih = (const float*)d_in[32];
  const float* lstm_bhh = (const float*)d_in[33];
  const float* out_w1   = (const float*)d_in[34];
  const float* out_b1   = (const float*)d_in[35];
  const float* out_w2   = (const float*)d_in[36];
  const float* out_b2   = (const float*)d_in[37];
  const float* out_w3   = (const float*)d_in[38];
  const float* out_b3   = (const float*)d_in[39];

  const int N = in_sizes[0]/8;
  const int E = in_sizes[1]/2;
  const int* srcA = eidx;
  const int* dstA = eidx + E;

  const int nb = (N+255)/256;
  const int S2SB = 256;

  char* wp = (char*)d_ws;
  auto alloc = [&](size_t bytes)->void*{ void* p=(void*)wp; wp += (bytes+255)&~(size_t)255; return p; };
  float* xhA   = (float*)alloc((size_t)N*CC*4);
  float* xhB   = (float*)alloc((size_t)N*CC*4);
  ushort* BT   = (ushort*)alloc((size_t)LL*131072*2);
  ushort* W2T  = (ushort*)alloc((size_t)16384*2);
  float* a_e   = (float*)alloc((size_t)LL*E*HH*4);
  float* asrc  = (float*)alloc((size_t)N*HH*4);
  float* adst  = (float*)alloc((size_t)N*HH*4);
  int* counts  = (int*)alloc((size_t)N*4);
  int* offsets = (int*)alloc((size_t)(N+1)*4);
  int* cursor  = (int*)alloc((size_t)N*4);
  int* elist   = (int*)alloc((size_t)E*4);
  int* bsum    = (int*)alloc((size_t)nb*4);
  float* wattS = (float*)alloc((size_t)LL*CC*HH*4);
  float* wattD = (float*)alloc((size_t)LL*CC*HH*4);
  float* wattE = (float*)alloc((size_t)LL*CC*HH*4);
  float* We    = (float*)alloc(4*CC*4);
  float* be    = (float*)alloc(CC*4);
  float* vemb  = (float*)alloc(CC*4);
  float* Wh1   = (float*)alloc(4*CC*4);
  float* bh1   = (float*)alloc(CC*4);
  float* aelin = (float*)alloc(48*4);
  float* aebias= (float*)alloc(12*4);
  float* vvec  = (float*)alloc(CC*4);
  float* lbuf  = (float*)alloc(4*CC*4);
  float* hS=lbuf; float* cS=lbuf+CC; float* qstar=lbuf+2*CC;
  float* pm    = (float*)alloc((size_t)S2SB*4);
  float* ps    = (float*)alloc((size_t)S2SB*4);
  float* pr    = (float*)alloc((size_t)S2SB*128*4);

  k_att_collapse<<<6,256,0,stream>>>(gat_w, att_src, wattS);
  k_att_collapse<<<6,256,0,stream>>>(gat_w, att_dst, wattD);
  k_att_collapse<<<6,256,0,stream>>>(gat_we, att_e, wattE);
  k_We<<<2,256,0,stream>>>(w_ee, w_ep, We);
  k_be_vemb<<<1,256,0,stream>>>(b_ee, w_ep, b_ep, vnf, w_vnf, b_vnf, be, vemb);
  k_h1eff<<<3,256,0,stream>>>(We, be, vemb, attn_w1, attn_b1, Wh1, bh1);
  k_aelin<<<1,64,0,stream>>>(We, be, wattE, aelin, aebias);
  k_wsplit<<<(LL*512*CC+255)/256,256,0,stream>>>(gat_w, BT);
  k_w2split<<<(128*64+255)/256,256,0,stream>>>(attn_w2, W2T);
  k_vvec<<<1,CC,0,stream>>>(vnf, venc_w1, venc_b1, venc_w2, venc_b2, vvec);
  k_node_embed<<<(N*CC+255)/256,256,0,stream>>>(x, w_node, b_node, xhA, N);

  hipMemsetAsync(counts, 0, (size_t)N*4, stream);
  k_count<<<(E+255)/256,256,0,stream>>>(dstA, counts, E);
  k_scan_blk<<<nb,256,0,stream>>>(counts, offsets, bsum, N);
  k_scan_top<<<1,1024,0,stream>>>(bsum, nb);
  k_scan_add<<<nb,256,0,stream>>>(offsets, bsum, N, E);
  hipMemsetAsync(cursor, 0, (size_t)N*4, stream);
  k_fill<<<(E+255)/256,256,0,stream>>>(dstA, offsets, cursor, elist, E);

  k_edge_attn<<<(E+63)/64,128,0,stream>>>(edge_attr, Wh1, bh1, W2T, attn_b2, attn_w3, attn_b3, aelin, aebias, a_e, E);

  float* cur = xhA;
  float* nxt = xhB;
  for(int l=0;l<LL;l++){
    float* ael = a_e + (size_t)l*E*HH;
    k_node_ad<<<(N+31)/32,256,0,stream>>>(cur, wattS+(size_t)l*CC*HH, wattD+(size_t)l*CC*HH, asrc, adst, N);
    k_alpha<<<(N*4+255)/256,256,0,stream>>>(asrc, adst, offsets, elist, srcA, ael, N);
    k_agg_gemm<<<(N+31)/32,256,0,stream>>>(cur, srcA, ael, offsets, elist,
                                           BT+(size_t)l*131072,
                                           gat_b+(size_t)l*CC, ln_g+(size_t)l*CC, ln_b+(size_t)l*CC,
                                           nxt, N);
    float* tmp = cur; cur = nxt; nxt = tmp;
  }

  hipMemsetAsync(lbuf, 0, 4*CC*4, stream);
  for(int it=0; it<3; ++it){
    k_lstm<<<1,512,0,stream>>>(lstm_wih, lstm_whh, lstm_bih, lstm_bhh, qstar, hS, cS);
    k_s2s1<<<S2SB,256,0,stream>>>(cur, hS, pm, ps, pr, N);
    k_s2s2<<<1,1024,0,stream>>>(pm, ps, pr, hS, qstar, S2SB);
  }

  k_out<<<1,256,0,stream>>>(qstar, vvec, out_w1, out_b1, out_w2, out_b2, out_w3, out_b3, (float*)d_out);
}

// Round 12
// 776.382 us; speedup vs baseline: 1.7984x; 1.7984x over previous
//
#include <hip/hip_runtime.h>
#include <math.h>

#define CC 128
#define HH 4
#define LL 3
#define LNEPS 1e-5f

typedef unsigned int u32;
typedef unsigned short ushort;
typedef float f32x16 __attribute__((ext_vector_type(16)));
typedef __bf16 bf16x8 __attribute__((ext_vector_type(8)));
union Frag { uint4 q; bf16x8 b; };

__device__ __forceinline__ ushort bf16rne(float x){ u32 u=__float_as_uint(x); return (ushort)((u + 0x7FFF + ((u>>16)&1))>>16); }
__device__ __forceinline__ float bf2f(ushort h){ return __uint_as_float(((u32)h)<<16); }

// ---------------- tiny precompute kernels ----------------

__global__ void k_att_collapse(const float* __restrict__ W, const float* __restrict__ att, float* __restrict__ out){
  int idx = blockIdx.x*blockDim.x + threadIdx.x;
  if(idx >= LL*CC*HH) return;
  int h = idx % HH; int k = (idx/HH)%CC; int l = idx/(HH*CC);
  const float* w = W + ((size_t)(l*CC+k))*(HH*CC) + h*CC;
  const float* a = att + (size_t)(l*HH+h)*CC;
  float s=0.f;
  for(int c=0;c<CC;c++) s += w[c]*a[c];
  out[idx] = s;
}

__global__ void k_We(const float* __restrict__ w_ee, const float* __restrict__ w_ep, float* __restrict__ We){
  int idx = blockIdx.x*blockDim.x + threadIdx.x;
  if(idx >= 4*CC) return;
  int c = idx & (CC-1); int k = idx >> 7;
  float s=0.f;
  for(int m=0;m<CC;m++) s += w_ee[k*CC+m]*w_ep[m*CC+c];
  We[idx]=s;
}

__global__ void k_be_vemb(const float* __restrict__ b_ee, const float* __restrict__ w_ep, const float* __restrict__ b_ep,
                          const float* __restrict__ vnf, const float* __restrict__ w_vnf, const float* __restrict__ b_vnf,
                          float* __restrict__ be, float* __restrict__ vemb){
  int t = threadIdx.x;
  if(t<CC){
    float s=b_ep[t];
    for(int m=0;m<CC;m++) s += b_ee[m]*w_ep[m*CC+t];
    be[t]=s;
  } else if(t<2*CC){
    int c=t-CC;
    float s=b_vnf[c];
    for(int j=0;j<6;j++) s += vnf[j]*w_vnf[j*CC+c];
    vemb[c]=s;
  }
}

__global__ void k_h1eff(const float* __restrict__ We, const float* __restrict__ be, const float* __restrict__ vemb,
                        const float* __restrict__ w1, const float* __restrict__ b1,
                        float* __restrict__ Wh1, float* __restrict__ bh1){
  int idx = blockIdx.x*blockDim.x + threadIdx.x;
  if(idx < 4*CC){
    int c = idx & (CC-1); int k = idx>>7;
    float s=0.f;
    for(int m=0;m<CC;m++) s += We[k*CC+m]*w1[m*CC+c];
    Wh1[idx]=s;
  } else if(idx < 5*CC){
    int c = idx - 4*CC;
    float s=b1[c];
    for(int m=0;m<CC;m++) s += be[m]*w1[m*CC+c];
    for(int j=0;j<CC;j++) s += vemb[j]*w1[(CC+j)*CC+c];
    bh1[c]=s;
  }
}

__global__ void k_aelin(const float* __restrict__ We, const float* __restrict__ be, const float* __restrict__ wattE,
                        float* __restrict__ aelin, float* __restrict__ aebias){
  int t = threadIdx.x;
  if(t<48){
    int l=t>>4, k=(t>>2)&3, h=t&3;
    float s=0.f;
    for(int m=0;m<CC;m++) s += We[k*CC+m]*wattE[(size_t)(l*CC+m)*HH+h];
    aelin[t]=s;
  } else if(t<60){
    int i=t-48; int l=i>>2, h=i&3;
    float s=0.f;
    for(int m=0;m<CC;m++) s += be[m]*wattE[(size_t)(l*CC+m)*HH+h];
    aebias[i]=s;
  }
}

// split + transpose + MFMA-tile W, hi/lo interleaved: [subtile(c/32*64+hk/8)][c%32][8 hi | 8 lo]
__global__ void k_wsplit(const float* __restrict__ gat_w, ushort* __restrict__ BT){
  int idx = blockIdx.x*blockDim.x + threadIdx.x;
  if(idx >= LL*512*CC) return;
  int l = idx >> 16;
  int r = idx & 65535;
  int hk = r >> 7;
  int c  = r & 127;
  int k = hk & 127, h = hk >> 7;
  float v = gat_w[((size_t)(l*CC + k))*(HH*CC) + h*CC + c] * 0.25f;
  ushort hi = bf16rne(v);
  ushort lo = bf16rne(v - bf2f(hi));
  size_t pos = (size_t)l*131072 + ((size_t)(c>>5)*64 + (hk>>3))*512 + (size_t)((c&31)*16 + (hk&7));
  BT[pos]=hi; BT[pos+8]=lo;
}

// w2 [128 k][64 o] -> B-fragment tiles: [(o/32)*16 + k/8][o%32][8 hi | 8 lo]
__global__ void k_w2split(const float* __restrict__ w2, ushort* __restrict__ W2T){
  int idx = blockIdx.x*blockDim.x + threadIdx.x;
  if(idx >= 128*64) return;
  int k = idx>>6, o = idx&63;
  float v = w2[idx];
  ushort hi = bf16rne(v);
  ushort lo = bf16rne(v - bf2f(hi));
  size_t pos = ((size_t)(o>>5)*16 + (k>>3))*512 + (size_t)((o&31)*16 + (k&7));
  W2T[pos]=hi; W2T[pos+8]=lo;
}

__global__ void k_vvec(const float* __restrict__ vnf, const float* __restrict__ w1, const float* __restrict__ b1,
                       const float* __restrict__ w2, const float* __restrict__ b2, float* __restrict__ v){
  __shared__ float hv[CC];
  int t=threadIdx.x;
  float s=b1[t];
  for(int j=0;j<6;j++) s += vnf[j]*w1[j*CC+t];
  hv[t]=fmaxf(s,0.f);
  __syncthreads();
  float o=b2[t];
  for(int j=0;j<CC;j++) o += hv[j]*w2[j*CC+t];
  v[t]=o;
}

// ---------------- node embedding ----------------
__global__ void k_node_embed(const float* __restrict__ x, const float* __restrict__ w, const float* __restrict__ b,
                             float* __restrict__ xh, int N){
  int idx=blockIdx.x*blockDim.x+threadIdx.x;
  if(idx>=N*CC) return;
  int c=idx&(CC-1); int n=idx>>7;
  const float* xr = x+(size_t)n*8;
  float s=b[c];
  #pragma unroll
  for(int k=0;k<8;k++) s += xr[k]*w[k*CC+c];
  xh[idx]=s;
}

// ---------------- CSR by dst (hierarchical scan) ----------------
__global__ void k_count(const int* __restrict__ dst, int* __restrict__ counts, int E){
  int e=blockIdx.x*blockDim.x+threadIdx.x;
  if(e<E) atomicAdd(&counts[dst[e]],1);
}

__global__ __launch_bounds__(256) void k_scan_blk(const int* __restrict__ counts, int* __restrict__ offsets,
                                                  int* __restrict__ bsum, int N){
  __shared__ int sv[256];
  int t=threadIdx.x; int i=blockIdx.x*256+t;
  int v = (i<N)? counts[i] : 0;
  sv[t]=v;
  __syncthreads();
  for(int off=1;off<256;off<<=1){
    int add = (t>=off)? sv[t-off]:0;
    __syncthreads();
    sv[t]+=add;
    __syncthreads();
  }
  if(i<N) offsets[i]=sv[t]-v;
  if(t==255) bsum[blockIdx.x]=sv[255];
}

__global__ __launch_bounds__(1024) void k_scan_top(int* __restrict__ bsum, int nb){
  __shared__ int sv[1024];
  int t=threadIdx.x;
  int v = (t<nb)? bsum[t] : 0;
  sv[t]=v;
  __syncthreads();
  for(int off=1;off<1024;off<<=1){
    int add = (t>=off)? sv[t-off]:0;
    __syncthreads();
    sv[t]+=add;
    __syncthreads();
  }
  if(t<nb) bsum[t]=sv[t]-v;
}

__global__ void k_scan_add(int* __restrict__ offsets, const int* __restrict__ bsum, int N, int E){
  int i=blockIdx.x*blockDim.x+threadIdx.x;
  if(i<N) offsets[i]+=bsum[i>>8];
  if(i==0) offsets[N]=E;
}

__global__ void k_fill(const int* __restrict__ dst, const int* __restrict__ offsets, int* __restrict__ cursor,
                       int* __restrict__ elist, int E){
  int e=blockIdx.x*blockDim.x+threadIdx.x;
  if(e<E){ int d=dst[e]; int pos=atomicAdd(&cursor[d],1); elist[offsets[d]+pos]=e; }
}

// ---------------- MFMA edge-attention MLP -> a_e[l][e][h] ----------------
__global__ __launch_bounds__(128) void k_edge_attn(
    const float* __restrict__ edge_attr,
    const float* __restrict__ Wh1, const float* __restrict__ bh1,
    const ushort* __restrict__ W2T, const float* __restrict__ attn_b2,
    const float* __restrict__ attn_w3, const float* __restrict__ attn_b3,
    const float* __restrict__ aelin, const float* __restrict__ aebias,
    float* __restrict__ a_e, int E)
{
  __shared__ __align__(16) ushort h1f[2][16][32][16];
  __shared__ float s_wh1[640];
  __shared__ float s_ea[64][4];
  __shared__ float s_att[64];
  int t = threadIdx.x;
  int e0 = blockIdx.x*64;
  for(int i=t;i<640;i+=128) s_wh1[i] = (i<512)? Wh1[i] : bh1[i-512];
  if(t<64){
    int e=e0+t;
    float4 v = (e<E)? *(const float4*)&edge_attr[(size_t)e*4] : make_float4(0.f,0.f,0.f,0.f);
    s_ea[t][0]=v.x; s_ea[t][1]=v.y; s_ea[t][2]=v.z; s_ea[t][3]=v.w;
  }
  __syncthreads();
  for(int c=t; c<1024; c+=128){
    int e = c&63, kc = c>>6;
    int et = e>>5, row = e&31;
    float ea0=s_ea[e][0], ea1=s_ea[e][1], ea2=s_ea[e][2], ea3=s_ea[e][3];
    ushort hibuf[8], lobuf[8];
    #pragma unroll
    for(int j=0;j<8;j++){
      int k = kc*8+j;
      float v = s_wh1[512+k] + ea0*s_wh1[k] + ea1*s_wh1[128+k] + ea2*s_wh1[256+k] + ea3*s_wh1[384+k];
      v = fmaxf(v, 0.f);
      ushort hi = bf16rne(v);
      hibuf[j]=hi; lobuf[j]=bf16rne(v - bf2f(hi));
    }
    *(uint4*)&h1f[et][kc][row][0] = *(const uint4*)hibuf;
    *(uint4*)&h1f[et][kc][row][8] = *(const uint4*)lobuf;
  }
  __syncthreads();
  int wave=t>>6, lane=t&63;
  int rlane = lane&31, khalf = lane>>5;
  int et = wave;
  f32x16 acc[2];
  #pragma unroll
  for(int o=0;o<2;o++)
    #pragma unroll
    for(int j=0;j<16;j++) acc[o][j]=0.f;
  for(int ks=0; ks<8; ++ks){
    int kq = ks*2 + khalf;
    Frag ah, al;
    ah.q = *(const uint4*)&h1f[et][kq][rlane][0];
    al.q = *(const uint4*)&h1f[et][kq][rlane][8];
    #pragma unroll
    for(int o=0;o<2;o++){
      size_t bb = ((size_t)(o*16 + kq))*512 + (size_t)(rlane*16);
      Frag bh, bl;
      bh.q = *(const uint4*)(W2T + bb);
      bl.q = *(const uint4*)(W2T + bb + 8);
      acc[o] = __builtin_amdgcn_mfma_f32_32x32x16_bf16(ah.b, bh.b, acc[o], 0,0,0);
      acc[o] = __builtin_amdgcn_mfma_f32_32x32x16_bf16(ah.b, bl.b, acc[o], 0,0,0);
      acc[o] = __builtin_amdgcn_mfma_f32_32x32x16_bf16(al.b, bh.b, acc[o], 0,0,0);
    }
  }
  float b2c0 = attn_b2[rlane], b2c1 = attn_b2[rlane+32];
  float w3c0 = attn_w3[rlane], w3c1 = attn_w3[rlane+32];
  float b3v = attn_b3[0];
  #pragma unroll
  for(int reg=0; reg<16; ++reg){
    float val = fmaxf(acc[0][reg]+b2c0,0.f)*w3c0 + fmaxf(acc[1][reg]+b2c1,0.f)*w3c1;
    #pragma unroll
    for(int off=1; off<32; off<<=1) val += __shfl_xor(val, off);
    int rloc = (reg&3) + 8*(reg>>2) + 4*khalf;
    if(rlane==0) s_att[et*32 + rloc] = 1.f/(1.f+expf(-(val + b3v)));
  }
  __syncthreads();
  if(t<64){
    int e = e0+t;
    if(e<E){
      float att = s_att[t];
      float ea0=s_ea[t][0], ea1=s_ea[t][1], ea2=s_ea[t][2], ea3=s_ea[t][3];
      #pragma unroll
      for(int l=0;l<LL;l++){
        float4 v;
        float* out=(float*)&v;
        #pragma unroll
        for(int h=0;h<4;h++){
          out[h] = att*(ea0*aelin[(l*4+0)*4+h] + ea1*aelin[(l*4+1)*4+h]
                      + ea2*aelin[(l*4+2)*4+h] + ea3*aelin[(l*4+3)*4+h] + aebias[l*4+h]);
        }
        *(float4*)&a_e[((size_t)l*E+e)*4] = v;
      }
    }
  }
}

// ---------------- per-node attention logits (LDS-staged) ----------------
__global__ __launch_bounds__(256) void k_node_ad(const float* __restrict__ xh, const float* __restrict__ wS, const float* __restrict__ wD,
                          float* __restrict__ asrc, float* __restrict__ adst, int N){
  __shared__ float sx[32*129];
  __shared__ float sw[CC*8];
  int t = threadIdx.x;
  int n0 = blockIdx.x*32;
  for(int i=t;i<512;i+=256){ int k=i>>2, h=i&3; sw[k*8+h]=wS[i]; sw[k*8+4+h]=wD[i]; }
  int lim = (N-n0 < 32 ? N-n0 : 32)*128;
  for(int i=t;i<lim;i+=256){ int nl=i>>7, k=i&127; sx[nl*129+k] = xh[(size_t)n0*128 + i]; }
  __syncthreads();
  int node = t>>3, o = t&7;
  if(n0+node < N){
    const float* xr = sx + node*129;
    float s=0.f;
    #pragma unroll 8
    for(int k=0;k<CC;k++) s += xr[k]*sw[k*8+o];
    ((o<4)? asrc : adst)[(n0+node)*4 + (o&3)] = s;
  }
}

// ---------------- per-(node,head) softmax normalize of a_e (in place) ----------------
__global__ void k_alpha(const float* __restrict__ asrc, const float* __restrict__ adst,
                        const int* __restrict__ offsets, const int* __restrict__ elist,
                        const int* __restrict__ srcArr, float* __restrict__ ael, int N){
  int idx = blockIdx.x*blockDim.x + threadIdx.x;
  if(idx >= N*4) return;
  int n = idx>>2, h = idx&3;
  int beg = offsets[n], end = offsets[n+1];
  if(beg==end) return;
  float ad = adst[n*4+h];
  float m = -1e30f;
  for(int i=beg;i<end;i++){
    int e = elist[i];
    float a = asrc[srcArr[e]*4+h] + ad + ael[e*4+h];
    a = (a>0.f)? a : 0.2f*a;
    m = fmaxf(m,a);
  }
  float s=0.f;
  for(int i=beg;i<end;i++){
    int e = elist[i];
    float a = asrc[srcArr[e]*4+h] + ad + ael[e*4+h];
    a = (a>0.f)? a : 0.2f*a;
    float ex = expf(a-m);
    s += ex;
    ael[e*4+h] = ex;
  }
  float inv = 1.f/(s+1e-16f);
  for(int i=beg;i<end;i++){
    int e = elist[i];
    ael[e*4+h] *= inv;
  }
}

// ---------------- per-dst GAT aggregation -> LDS-staged full-line writes ----------------
__global__ __launch_bounds__(256) void k_aggregate(
    const float* __restrict__ xh, const int* __restrict__ srcArr,
    const float* __restrict__ alpha, const int* __restrict__ offsets, const int* __restrict__ elist,
    ushort* __restrict__ AB, int N)
{
  __shared__ __align__(16) ushort sAB[4][64][16];
  int wave = threadIdx.x>>6, lane = threadIdx.x&63;
  int n = blockIdx.x*4+wave;
  float2 ac[4];
  #pragma unroll
  for(int h=0;h<4;h++){ ac[h].x=0.f; ac[h].y=0.f; }
  if(n<N){
    int beg = offsets[n], end = offsets[n+1];
    const float4* al4 = (const float4*)alpha;
    for(int i=beg;i<end;i++){
      int e = elist[i];
      int sr = srcArr[e];
      float4 a = al4[e];
      float2 x = *(const float2*)&xh[(size_t)sr*CC + lane*2];
      ac[0].x += a.x*x.x; ac[0].y += a.x*x.y;
      ac[1].x += a.y*x.x; ac[1].y += a.y*x.y;
      ac[2].x += a.z*x.x; ac[2].y += a.z*x.y;
      ac[3].x += a.w*x.x; ac[3].y += a.w*x.y;
    }
  }
  #pragma unroll
  for(int h=0;h<4;h++){
    ushort h0 = bf16rne(ac[h].x), h1 = bf16rne(ac[h].y);
    u32 hi = (u32)h0 | ((u32)h1<<16);
    u32 lo = (u32)bf16rne(ac[h].x - bf2f(h0)) | ((u32)bf16rne(ac[h].y - bf2f(h1))<<16);
    int hk = h*CC + lane*2;
    int st = hk>>3, off = hk&7;
    *(u32*)&sAB[wave][st][off]   = hi;
    *(u32*)&sAB[wave][st][off+8] = lo;
  }
  __syncthreads();
  int n0 = blockIdx.x*4;
  size_t tilebase = ((size_t)(n0>>5))*32768 + (size_t)((n0&31)*16);
  for(int i=threadIdx.x; i<512; i+=256){
    int st = i>>3, p = i&7;
    uint4 v = *(const uint4*)&sAB[p>>1][st][(p&1)*8];
    *(uint4*)&AB[tilebase + (size_t)st*512 + (size_t)p*8] = v;
  }
}

// ---------------- MFMA split-bf16 GEMM [N,512]@[512,128] + bias + LN + residual (BM=64) ----------------
__global__ __launch_bounds__(128) void k_gemm_ln_mfma(
    const ushort* __restrict__ AB, const ushort* __restrict__ BT,
    const float* __restrict__ bias, const float* __restrict__ lng, const float* __restrict__ lnb,
    float* __restrict__ xh, int N)
{
  int tid = threadIdx.x;
  int w = tid>>6, lane = tid&63;
  int rlane = lane&31, khalf = lane>>5;
  int rb = blockIdx.x*2 + w;
  f32x16 acc[4];
  #pragma unroll
  for(int t=0;t<4;t++)
    #pragma unroll
    for(int j=0;j<16;j++) acc[t][j]=0.f;

  const size_t laneoff = (size_t)(rlane*16);
  for(int ks=0; ks<32; ++ks){
    int kq = ks*2 + khalf;
    size_t base = ((size_t)(rb*64 + kq))*512 + laneoff;
    Frag ah, al;
    ah.q = *(const uint4*)(AB + base);
    al.q = *(const uint4*)(AB + base + 8);
    #pragma unroll
    for(int t=0;t<4;t++){
      size_t bb = ((size_t)(t*64 + kq))*512 + laneoff;
      Frag bh, bl;
      bh.q = *(const uint4*)(BT + bb);
      bl.q = *(const uint4*)(BT + bb + 8);
      acc[t] = __builtin_amdgcn_mfma_f32_32x32x16_bf16(ah.b, bh.b, acc[t], 0,0,0);
      acc[t] = __builtin_amdgcn_mfma_f32_32x32x16_bf16(ah.b, bl.b, acc[t], 0,0,0);
      acc[t] = __builtin_amdgcn_mfma_f32_32x32x16_bf16(al.b, bh.b, acc[t], 0,0,0);
    }
  }
  float bias4[4], g4[4], eb4[4];
  #pragma unroll
  for(int t=0;t<4;t++){ int c=t*32+rlane; bias4[t]=bias[c]; g4[t]=lng[c]; eb4[t]=lnb[c]; }
  #pragma unroll
  for(int reg=0; reg<16; ++reg){
    int rloc = (reg&3) + 8*(reg>>2) + 4*khalf;
    int grow = rb*32 + rloc;
    float x0=acc[0][reg]+bias4[0];
    float x1=acc[1][reg]+bias4[1];
    float x2=acc[2][reg]+bias4[2];
    float x3=acc[3][reg]+bias4[3];
    float s = x0+x1+x2+x3;
    #pragma unroll
    for(int off=1; off<32; off<<=1) s += __shfl_xor(s, off);
    float mu = s*(1.f/CC);
    x0-=mu; x1-=mu; x2-=mu; x3-=mu;
    float q = x0*x0+x1*x1+x2*x2+x3*x3;
    #pragma unroll
    for(int off=1; off<32; off<<=1) q += __shfl_xor(q, off);
    float inv = rsqrtf(q*(1.f/CC)+LNEPS);
    if(grow < N){
      size_t gi = (size_t)grow*CC + rlane;
      xh[gi+ 0]  = x0*inv*g4[0] + eb4[0] + xh[gi+ 0];
      xh[gi+32]  = x1*inv*g4[1] + eb4[1] + xh[gi+32];
      xh[gi+64]  = x2*inv*g4[2] + eb4[2] + xh[gi+64];
      xh[gi+96]  = x3*inv*g4[3] + eb4[3] + xh[gi+96];
    }
  }
}

// ---------------- Set2Set ----------------
__global__ __launch_bounds__(512) void k_lstm(const float* __restrict__ wih, const float* __restrict__ whh,
                    const float* __restrict__ bih, const float* __restrict__ bhh,
                    const float* __restrict__ qstar, float* __restrict__ hS, float* __restrict__ cS){
  __shared__ float sq[2*CC];
  __shared__ float sh[CC];
  __shared__ float sg[4*CC];
  int t=threadIdx.x;
  if(t<2*CC) sq[t]=qstar[t];
  else if(t<3*CC) sh[t-2*CC]=hS[t-2*CC];
  __syncthreads();
  float a=bih[t]+bhh[t];
  const float* wr = wih + (size_t)t*2*CC;
  for(int j=0;j<2*CC;j++) a += wr[j]*sq[j];
  const float* hr = whh + (size_t)t*CC;
  for(int j=0;j<CC;j++) a += hr[j]*sh[j];
  sg[t]=a;
  __syncthreads();
  if(t<CC){
    float gi=sg[t], gf=sg[CC+t], gg=sg[2*CC+t], go=sg[3*CC+t];
    float c = 1.f/(1.f+expf(-gf))*cS[t] + 1.f/(1.f+expf(-gi))*tanhf(gg);
    float h = 1.f/(1.f+expf(-go))*tanhf(c);
    cS[t]=c; hS[t]=h;
  }
}

__global__ __launch_bounds__(256) void k_s2s1(const float* __restrict__ xh, const float* __restrict__ q,
                                              float* __restrict__ pm, float* __restrict__ ps,
                                              float* __restrict__ pr, int N){
  int t=threadIdx.x, wave=t>>6, lane=t&63;
  float q0=q[lane], q1=q[lane+64];
  float m=-1e30f, s=0.f, r0=0.f, r1=0.f;
  for(int n=blockIdx.x*4+wave; n<N; n+=gridDim.x*4){
    const float* xr = xh+(size_t)n*CC;
    float x0 = xr[lane], x1 = xr[lane+64];
    float v = x0*q0 + x1*q1;
    #pragma unroll
    for(int o=32;o>=1;o>>=1) v += __shfl_xor(v,o);
    float nm = fmaxf(m,v);
    float f = expf(m-nm), g = expf(v-nm);
    s = s*f + g; r0 = r0*f + g*x0; r1 = r1*f + g*x1;
    m = nm;
  }
  __shared__ float sm[4], ss[4], sr[4][128];
  if(lane==0){ sm[wave]=m; ss[wave]=s; }
  sr[wave][lane]=r0; sr[wave][lane+64]=r1;
  __syncthreads();
  if(t<128){
    float M = fmaxf(fmaxf(sm[0],sm[1]),fmaxf(sm[2],sm[3]));
    float e0=expf(sm[0]-M), e1=expf(sm[1]-M), e2=expf(sm[2]-M), e3=expf(sm[3]-M);
    pr[(size_t)blockIdx.x*128+t] = sr[0][t]*e0 + sr[1][t]*e1 + sr[2][t]*e2 + sr[3][t]*e3;
    if(t==0){ pm[blockIdx.x]=M; ps[blockIdx.x]= ss[0]*e0+ss[1]*e1+ss[2]*e2+ss[3]*e3; }
  }
}

__global__ __launch_bounds__(1024) void k_s2s2(const float* __restrict__ pm, const float* __restrict__ ps,
                                               const float* __restrict__ pr, const float* __restrict__ hS,
                                               float* __restrict__ qstar, int NB){
  __shared__ float sM[256];
  __shared__ float sw[256];
  __shared__ float sS[256];
  __shared__ float srs[8][128];
  int t = threadIdx.x;
  if(t<256) sM[t] = (t<NB)? pm[t] : -1e30f;
  __syncthreads();
  for(int off=128; off>=1; off>>=1){
    if(t<off) sM[t] = fmaxf(sM[t], sM[t+off]);
    __syncthreads();
  }
  float M = sM[0];
  if(t<256){
    float w = (t<NB)? expf(pm[t]-M) : 0.f;
    sw[t] = w;
    sS[t] = (t<NB)? ps[t]*w : 0.f;
  }
  __syncthreads();
  for(int off=128; off>=1; off>>=1){
    if(t<off) sS[t] += sS[t+off];
    __syncthreads();
  }
  float ssum = sS[0];
  int g = t>>7, col = t&127;
  float rs = 0.f;
  for(int b=g; b<NB; b+=8) rs += pr[(size_t)b*128+col]*sw[b];
  srs[g][col] = rs;
  __syncthreads();
  if(t<128){
    float r = srs[0][t]+srs[1][t]+srs[2][t]+srs[3][t]+srs[4][t]+srs[5][t]+srs[6][t]+srs[7][t];
    qstar[t]    = hS[t];
    qstar[CC+t] = r/ssum;
  }
}

// ---------------- output MLP ----------------
__global__ __launch_bounds__(256) void k_out(
  const float* __restrict__ qstar, const float* __restrict__ vvec,
  const float* __restrict__ w1, const float* __restrict__ b1,
  const float* __restrict__ w2, const float* __restrict__ b2,
  const float* __restrict__ w3, const float* __restrict__ b3, float* __restrict__ out)
{
  __shared__ float comb[3*CC];
  __shared__ float o1[CC];
  __shared__ float o2[64];
  int t=threadIdx.x;
  if(t<2*CC) comb[t]=qstar[t];
  if(t<CC) comb[2*CC+t]=vvec[t];
  __syncthreads();
  if(t<CC){
    float a=b1[t];
    for(int j=0;j<3*CC;j++) a += comb[j]*w1[j*CC+t];
    o1[t]=fmaxf(a,0.f);
  }
  __syncthreads();
  if(t<64){
    float a=b2[t];
    for(int j=0;j<CC;j++) a += o1[j]*w2[j*64+t];
    o2[t]=fmaxf(a,0.f);
  }
  __syncthreads();
  {
    float a=b3[t];
    for(int j=0;j<64;j++) a += o2[j]*w3[j*256+t];
    out[t]=fmaxf(a,0.f);
  }
}

extern "C" void kernel_launch(void* const* d_in, const int* in_sizes, int n_in,
                              void* d_out, int out_size, void* d_ws, size_t ws_size,
                              hipStream_t stream){
  (void)n_in; (void)out_size; (void)ws_size;
  const float* x        = (const float*)d_in[0];
  const int*   eidx     = (const int*)  d_in[1];
  const float* edge_attr= (const float*)d_in[2];
  const float* vnf      = (const float*)d_in[3];
  const float* w_node   = (const float*)d_in[4];
  const float* b_node   = (const float*)d_in[5];
  const float* w_ee     = (const float*)d_in[6];
  const float* b_ee     = (const float*)d_in[7];
  const float* w_ep     = (const float*)d_in[8];
  const float* b_ep     = (const float*)d_in[9];
  const float* w_vnf    = (const float*)d_in[10];
  const float* b_vnf    = (const float*)d_in[11];
  const float* attn_w1  = (const float*)d_in[12];
  const float* attn_b1  = (const float*)d_in[13];
  const float* attn_w2  = (const float*)d_in[14];
  const float* attn_b2  = (const float*)d_in[15];
  const float* attn_w3  = (const float*)d_in[16];
  const float* attn_b3  = (const float*)d_in[17];
  const float* gat_w    = (const float*)d_in[18];
  const float* att_src  = (const float*)d_in[19];
  const float* att_dst  = (const float*)d_in[20];
  const float* gat_we   = (const float*)d_in[21];
  const float* att_e    = (const float*)d_in[22];
  const float* gat_b    = (const float*)d_in[23];
  const float* ln_g     = (const float*)d_in[24];
  const float* ln_b     = (const float*)d_in[25];
  const float* venc_w1  = (const float*)d_in[26];
  const float* venc_b1  = (const float*)d_in[27];
  const float* venc_w2  = (const float*)d_in[28];
  const float* venc_b2  = (const float*)d_in[29];
  const float* lstm_wih = (const float*)d_in[30];
  const float* lstm_whh = (const float*)d_in[31];
  const float* lstm_bih = (const float*)d_in[32];
  const float* lstm_bhh = (const float*)d_in[33];
  const float* out_w1   = (const float*)d_in[34];
  const float* out_b1   = (const float*)d_in[35];
  const float* out_w2   = (const float*)d_in[36];
  const float* out_b2   = (const float*)d_in[37];
  const float* out_w3   = (const float*)d_in[38];
  const float* out_b3   = (const float*)d_in[39];

  const int N = in_sizes[0]/8;
  const int E = in_sizes[1]/2;
  const int* srcA = eidx;
  const int* dstA = eidx + E;

  const int Npad = ((N+127)/128)*128;
  const size_t asize = (size_t)Npad*1024;
  const int nb = (N+255)/256;
  const int S2SB = 256;

  char* wp = (char*)d_ws;
  auto alloc = [&](size_t bytes)->void*{ void* p=(void*)wp; wp += (bytes+255)&~(size_t)255; return p; };
  float* xh    = (float*)alloc((size_t)N*CC*4);
  ushort* AB   = (ushort*)alloc(asize*2);
  ushort* BT   = (ushort*)alloc((size_t)LL*131072*2);
  ushort* W2T  = (ushort*)alloc((size_t)16384*2);
  float* a_e   = (float*)alloc((size_t)LL*E*HH*4);
  float* asrc  = (float*)alloc((size_t)N*HH*4);
  float* adst  = (float*)alloc((size_t)N*HH*4);
  int* counts  = (int*)alloc((size_t)N*4);
  int* offsets = (int*)alloc((size_t)(N+1)*4);
  int* cursor  = (int*)alloc((size_t)N*4);
  int* elist   = (int*)alloc((size_t)E*4);
  int* bsum    = (int*)alloc((size_t)nb*4);
  float* wattS = (float*)alloc((size_t)LL*CC*HH*4);
  float* wattD = (float*)alloc((size_t)LL*CC*HH*4);
  float* wattE = (float*)alloc((size_t)LL*CC*HH*4);
  float* We    = (float*)alloc(4*CC*4);
  float* be    = (float*)alloc(CC*4);
  float* vemb  = (float*)alloc(CC*4);
  float* Wh1   = (float*)alloc(4*CC*4);
  float* bh1   = (float*)alloc(CC*4);
  float* aelin = (float*)alloc(48*4);
  float* aebias= (float*)alloc(12*4);
  float* vvec  = (float*)alloc(CC*4);
  float* lbuf  = (float*)alloc(4*CC*4);
  float* hS=lbuf; float* cS=lbuf+CC; float* qstar=lbuf+2*CC;
  float* pm    = (float*)alloc((size_t)S2SB*4);
  float* ps    = (float*)alloc((size_t)S2SB*4);
  float* pr    = (float*)alloc((size_t)S2SB*128*4);

  k_att_collapse<<<6,256,0,stream>>>(gat_w, att_src, wattS);
  k_att_collapse<<<6,256,0,stream>>>(gat_w, att_dst, wattD);
  k_att_collapse<<<6,256,0,stream>>>(gat_we, att_e, wattE);
  k_We<<<2,256,0,stream>>>(w_ee, w_ep, We);
  k_be_vemb<<<1,256,0,stream>>>(b_ee, w_ep, b_ep, vnf, w_vnf, b_vnf, be, vemb);
  k_h1eff<<<3,256,0,stream>>>(We, be, vemb, attn_w1, attn_b1, Wh1, bh1);
  k_aelin<<<1,64,0,stream>>>(We, be, wattE, aelin, aebias);
  k_wsplit<<<(LL*512*CC+255)/256,256,0,stream>>>(gat_w, BT);
  k_w2split<<<(128*64+255)/256,256,0,stream>>>(attn_w2, W2T);
  k_vvec<<<1,CC,0,stream>>>(vnf, venc_w1, venc_b1, venc_w2, venc_b2, vvec);
  k_node_embed<<<(N*CC+255)/256,256,0,stream>>>(x, w_node, b_node, xh, N);

  hipMemsetAsync(counts, 0, (size_t)N*4, stream);
  k_count<<<(E+255)/256,256,0,stream>>>(dstA, counts, E);
  k_scan_blk<<<nb,256,0,stream>>>(counts, offsets, bsum, N);
  k_scan_top<<<1,1024,0,stream>>>(bsum, nb);
  k_scan_add<<<nb,256,0,stream>>>(offsets, bsum, N, E);
  hipMemsetAsync(cursor, 0, (size_t)N*4, stream);
  k_fill<<<(E+255)/256,256,0,stream>>>(dstA, offsets, cursor, elist, E);

  k_edge_attn<<<(E+63)/64,128,0,stream>>>(edge_attr, Wh1, bh1, W2T, attn_b2, attn_w3, attn_b3, aelin, aebias, a_e, E);

  for(int l=0;l<LL;l++){
    float* ael = a_e + (size_t)l*E*HH;
    k_node_ad<<<(N+31)/32,256,0,stream>>>(xh, wattS+(size_t)l*CC*HH, wattD+(size_t)l*CC*HH, asrc, adst, N);
    k_alpha<<<(N*4+255)/256,256,0,stream>>>(asrc, adst, offsets, elist, srcA, ael, N);
    k_aggregate<<<(N+3)/4,256,0,stream>>>(xh, srcA, ael, offsets, elist, AB, N);
    k_gemm_ln_mfma<<<Npad/64,128,0,stream>>>(AB, BT+(size_t)l*131072,
                                             gat_b+(size_t)l*CC, ln_g+(size_t)l*CC, ln_b+(size_t)l*CC, xh, N);
  }

  hipMemsetAsync(lbuf, 0, 4*CC*4, stream);
  for(int it=0; it<3; ++it){
    k_lstm<<<1,512,0,stream>>>(lstm_wih, lstm_whh, lstm_bih, lstm_bhh, qstar, hS, cS);
    k_s2s1<<<S2SB,256,0,stream>>>(xh, hS, pm, ps, pr, N);
    k_s2s2<<<1,1024,0,stream>>>(pm, ps, pr, hS, qstar, S2SB);
  }

  k_out<<<1,256,0,stream>>>(qstar, vvec, out_w1, out_b1, out_w2, out_b2, out_w3, out_b3, (float*)d_out);
}